// Round 1
// baseline (241.372 us; speedup 1.0000x reference)
//
#include <hip/hip_runtime.h>

// NTN: out[n,k] = relu( cos(x1 @ W1[k], x2 @ W2[k]) + [x1,x2]·V[k] + b[k] )
// N=32768, D=128, K=16.
// R4 = R3 + occupancy doubling. R3: 2 blocks/CU (8 waves/CU, Occupancy 16.8%),
// stall-bound (MfmaUtil 26.5%, VALUBusy 30%, both pipes underfed at 2 waves/SIMD).
// Same math, same per-wave inner loop, same prep layout; only concurrency changes:
//  - k split 4 ways: kq = 4 k's per block (chunk range [kq*8, kq*8+8)).
//  - 512-thread / 8-wave blocks, 256 rows/block (still 32 rows/wave, nt=2).
//  - grid 512 = 128 rb x 4 kq, XCD-major mapping: the 4 kq-blocks of one rb sit
//    adjacent on the SAME XCD so their 16B out-line quarters merge in its L2.
//  - LDS 2 x 32KB ping-pong -> 128KB/CU, 2 blocks/CU, 16 waves/CU = 4 waves/SIMD.
//    Same 64-MFMA-per-barrier schedule; stage is now 4 glds/wave (8 waves).
//  - per-block W L2 traffic halves (8 chunks vs 16).

typedef __attribute__((ext_vector_type(8))) __bf16 bf16x8;
typedef __attribute__((ext_vector_type(8))) unsigned short us8;
typedef __attribute__((ext_vector_type(4))) float f32x4;

static __device__ __forceinline__ unsigned short f2bf(float f) {
  unsigned u = __float_as_uint(f);
  u += 0x7FFFu + ((u >> 16) & 1u);   // round-to-nearest-even
  return (unsigned short)(u >> 16);
}

static __device__ __forceinline__ bf16x8 as_bf(us8 u) {
  bf16x8 r;
  __builtin_memcpy(&r, &u, sizeof(r));
  return r;
}

// ---------------- prep (UNCHANGED from R3) ----------------
// wsW: 32 chunks (cc = k*2 + h) of 2048 16B-units.
//   unit u: side=(u>>10)&1, et'=(u>>8)&3, s=(u>>6)&3, lane=u&63.
//   frag[j] = W_side[k][d = s*32 + (lane>>4)*8 + j][e = (h*4+et')*16 + (lane&15)]
// wsV: unit cs*64+lane: frag[j] = V[lane&15][c = cs*32 + (lane>>4)*8 + j]
__global__ void ntn_prep(const float* __restrict__ W1, const float* __restrict__ W2,
                         const float* __restrict__ V,
                         unsigned short* __restrict__ wsW, unsigned short* __restrict__ wsV) {
  int t = blockIdx.x * 256 + threadIdx.x;
  if (t < 65536) {
    int u = t & 2047;
    int lane = u & 63, s = (u >> 6) & 3, et2 = (u >> 8) & 3, side = (u >> 10) & 1;
    int cc = t >> 11, h = cc & 1, k = cc >> 1;
    int q = lane >> 4, l15 = lane & 15;
    int et = h * 4 + et2;
    const float* W = side ? W2 : W1;
    const float* src = W + k * 16384 + (s * 32 + q * 8) * 128 + (et * 16 + l15);
    us8 r;
#pragma unroll
    for (int j = 0; j < 8; ++j) r[j] = f2bf(src[j * 128]);
    *(us8*)(wsW + (size_t)t * 8) = r;
  } else if (t < 66048) {
    int u = t - 65536;
    int lane = u & 63, cs = u >> 6;
    int q = lane >> 4, l15 = lane & 15;
    const float* src = V + l15 * 256 + cs * 32 + q * 8;
    us8 r;
#pragma unroll
    for (int j = 0; j < 8; ++j) r[j] = f2bf(src[j]);
    *(us8*)(wsV + (size_t)u * 8) = r;
  }
}

// ---------------- main ----------------
__global__ __launch_bounds__(512, 4) void ntn_main(
    const float* __restrict__ x1, const float* __restrict__ x2,
    const float* __restrict__ b,
    const unsigned short* __restrict__ wsW, const unsigned short* __restrict__ wsV,
    float* __restrict__ out) {
  __shared__ uint4 ldsW[2][2048];   // two 32KB chunk slots = 64KB

  const int tid = threadIdx.x;
  const int lane = tid & 63, wave = tid >> 6;   // wave 0..7
  const int q = lane >> 4, l15 = lane & 15;

  // XCD-major block mapping: blocks dispatch round-robin across 8 XCDs, so
  // bi&7 is the XCD. Give each XCD a contiguous 16-rb slab; within it the
  // 4 kq-blocks of one rb are adjacent (same XCD -> out-line quarters merge).
  const int bi = blockIdx.x;
  const int xcd = bi & 7, jj = bi >> 3;
  const int rb = xcd * 16 + (jj >> 2);    // 0..127: 256-row group
  const int kq = jj & 3;                  // k range [kq*4, kq*4+4)
  const int rowbase = rb * 256 + wave * 32;

  const f32x4 zero4 = {0.f, 0.f, 0.f, 0.f};

  // async stage of one 32KB chunk into an LDS slot (4 glds x 64 lanes x 16B / wave)
  auto stage = [&](int cc, int slot) {
    const unsigned short* src = wsW + (size_t)cc * 16384 + (size_t)(wave * 256 + lane) * 8;
    uint4* dst = &ldsW[slot][wave * 256];
#pragma unroll
    for (int i = 0; i < 4; ++i)
      __builtin_amdgcn_global_load_lds(
          (__attribute__((address_space(1))) void*)(void*)(src + i * 512),
          (__attribute__((address_space(3))) void*)(dst + i * 64), 16, 0, 0);
  };

  stage(kq * 8, 0);   // first chunk of our k range

  // ---- X fragments (B-operand), bf16, k-invariant, in registers ----
  // frag[j] = X[row = rowbase + nt*16 + (lane&15)][d = s*32 + (lane>>4)*8 + j]
  bf16x8 xb[2][2][4];
#pragma unroll
  for (int side = 0; side < 2; ++side) {
    const float* xp0 = side ? x2 : x1;
#pragma unroll
    for (int nt = 0; nt < 2; ++nt) {
#pragma unroll
      for (int s = 0; s < 4; ++s) {
        const float* p = xp0 + (size_t)(rowbase + nt * 16 + l15) * 128 + s * 32 + q * 8;
        float4 v0 = *(const float4*)p;
        float4 v1 = *(const float4*)(p + 4);
        us8 uu;
        uu[0] = f2bf(v0.x); uu[1] = f2bf(v0.y); uu[2] = f2bf(v0.z); uu[3] = f2bf(v0.w);
        uu[4] = f2bf(v1.x); uu[5] = f2bf(v1.y); uu[6] = f2bf(v1.z); uu[7] = f2bf(v1.w);
        xb[side][nt][s] = as_bf(uu);
      }
    }
  }

  // ---- part2 + b via MFMA (A = V frags: M=k; B = X frags), kept in registers ----
  f32x4 accP[2];
  {
    bf16x8 vf[8];
#pragma unroll
    for (int cs = 0; cs < 8; ++cs)
      vf[cs] = as_bf(*(const us8*)(wsV + (size_t)(cs * 64 + lane) * 8));
    float4 bv = *(const float4*)(b + q * 4);
#pragma unroll
    for (int nt = 0; nt < 2; ++nt) {
      f32x4 a = zero4;
#pragma unroll
      for (int cs = 0; cs < 8; ++cs)
        a = __builtin_amdgcn_mfma_f32_16x16x32_bf16(vf[cs], xb[cs >> 2][nt][cs & 3], a, 0, 0, 0);
      a.x += bv.x; a.y += bv.y; a.z += bv.z; a.w += bv.w;
      accP[nt] = a;   // lane quad q holds part2+b for k = q*4 + reg
    }
  }

  float nm[2] = {0.f, 0.f}, q1[2] = {0.f, 0.f}, q2[2] = {0.f, 0.f};

  // compute one e-half (4 e-tiles, both sides) from an LDS slot, fold reductions
  auto compute = [&](int slot) {
#pragma unroll
    for (int et = 0; et < 4; ++et) {
      bf16x8 wa[4], wb[4];
#pragma unroll
      for (int s = 0; s < 4; ++s) {
        wa[s] = as_bf(*(const us8*)&ldsW[slot][et * 256 + s * 64 + lane]);
        wb[s] = as_bf(*(const us8*)&ldsW[slot][1024 + et * 256 + s * 64 + lane]);
      }
#pragma unroll
      for (int nt = 0; nt < 2; ++nt) {
        f32x4 a1 = zero4, a2 = zero4;
#pragma unroll
        for (int s = 0; s < 4; ++s)
          a1 = __builtin_amdgcn_mfma_f32_16x16x32_bf16(wa[s], xb[0][nt][s], a1, 0, 0, 0);
#pragma unroll
        for (int s = 0; s < 4; ++s)
          a2 = __builtin_amdgcn_mfma_f32_16x16x32_bf16(wb[s], xb[1][nt][s], a2, 0, 0, 0);
        nm[nt] += a1.x * a2.x + a1.y * a2.y + a1.z * a2.z + a1.w * a2.w;
        q1[nt] += a1.x * a1.x + a1.y * a1.y + a1.z * a1.z + a1.w * a1.w;
        q2[nt] += a2.x * a2.x + a2.y * a2.y + a2.z * a2.z + a2.w * a2.w;
      }
    }
  };

#pragma unroll 1
  for (int kk = 0; kk < 4; ++kk) {
    const int cbase = kq * 8 + 2 * kk;
    __syncthreads();                       // chunk (kk, h=0) in slot0; slot1 free
    stage(cbase + 1, 1);
    compute(0);
    __syncthreads();                       // chunk (kk, h=1) in slot1; slot0 free
    if (kk < 3) stage(cbase + 2, 0);
    compute(1);

    const int k = kq * 4 + kk;
    const int qo = k >> 2;                 // owning lane quad (== kq)
    const int r  = k & 3;
#pragma unroll
    for (int nt = 0; nt < 2; ++nt) {
      float n = nm[nt], s1 = q1[nt], s2 = q2[nt];
      n  += __shfl_xor(n, 16);  n  += __shfl_xor(n, 32);
      s1 += __shfl_xor(s1, 16); s1 += __shfl_xor(s1, 32);
      s2 += __shfl_xor(s2, 16); s2 += __shfl_xor(s2, 32);
      float d1 = fmaxf(sqrtf(s1), 1e-8f);
      float d2 = fmaxf(sqrtf(s2), 1e-8f);
      float p1 = n / (d1 * d2);
      float pc = (r == 0) ? accP[nt].x : (r == 1) ? accP[nt].y
               : (r == 2) ? accP[nt].z : accP[nt].w;
      if (q == qo)
        out[(size_t)(rowbase + nt * 16 + l15) * 16 + k] = fmaxf(p1 + pc, 0.f);
      nm[nt] = 0.f; q1[nt] = 0.f; q2[nt] = 0.f;
    }
  }
}

extern "C" void kernel_launch(void* const* d_in, const int* in_sizes, int n_in,
                              void* d_out, int out_size, void* d_ws, size_t ws_size,
                              hipStream_t stream) {
  const float* x1 = (const float*)d_in[0];
  const float* x2 = (const float*)d_in[1];
  const float* W1 = (const float*)d_in[2];
  const float* W2 = (const float*)d_in[3];
  const float* V  = (const float*)d_in[4];
  const float* b  = (const float*)d_in[5];
  float* out = (float*)d_out;
  unsigned short* wsW = (unsigned short*)d_ws;
  unsigned short* wsV = wsW + (size_t)65536 * 8;   // 1MB offset

  ntn_prep<<<258, 256, 0, stream>>>(W1, W2, V, wsW, wsV);
  ntn_main<<<512, 512, 0, stream>>>(x1, x2, b, wsW, wsV, out);
}

// Round 3
// 124.386 us; speedup vs baseline: 1.9405x; 1.9405x over previous
//
#include <hip/hip_runtime.h>

// NTN: out[n,k] = relu( cos(x1 @ W1[k], x2 @ W2[k]) + [x1,x2]·V[k] + b[k] )
// N=32768, D=128, K=16.
// R6 = R4 (known-CORRECT 512-thr/8-wave restructure, absmax 0.03125) with the
// one-token fix: __launch_bounds__(512, 2) instead of (512, 4).
// R4 post-mortem: hipcc treats launch_bounds arg2 as BLOCKS/CU (CUDA semantics):
// (512,4) -> 4 blk x 8 waves = 8 waves/SIMD -> 64-VGPR cap -> xb[] spilled to
// scratch (FETCH 386MB / WRITE 260MB, MfmaUtil 8%). (512,2) -> 2 blk x 8 waves
// = 4 waves/SIMD -> 128-VGPR budget >= natural ~108 -> no spill, occupancy
// mechanism retained (R4 measured Occupancy 39% vs R3's 16.8%).
//  - k split 4 ways: kq = 4 k's per block (chunk range [kq*8, kq*8+8)).
//  - 512-thread / 8-wave blocks, 256 rows/block (still 32 rows/wave, nt=2).
//  - grid 512 = 128 rb x 4 kq, XCD-major: 4 kq-blocks of one rb adjacent on the
//    SAME XCD so their 16B out-line quarters merge in its L2.
//  - LDS 2 x 32KB ping-pong -> 128KB/CU at 2 blocks/CU, 16 waves/CU.

typedef __attribute__((ext_vector_type(8))) __bf16 bf16x8;
typedef __attribute__((ext_vector_type(8))) unsigned short us8;
typedef __attribute__((ext_vector_type(4))) float f32x4;

static __device__ __forceinline__ unsigned short f2bf(float f) {
  unsigned u = __float_as_uint(f);
  u += 0x7FFFu + ((u >> 16) & 1u);   // round-to-nearest-even
  return (unsigned short)(u >> 16);
}

static __device__ __forceinline__ bf16x8 as_bf(us8 u) {
  bf16x8 r;
  __builtin_memcpy(&r, &u, sizeof(r));
  return r;
}

// ---------------- prep (UNCHANGED) ----------------
// wsW: 32 chunks (cc = k*2 + h) of 2048 16B-units.
//   unit u: side=(u>>10)&1, et'=(u>>8)&3, s=(u>>6)&3, lane=u&63.
//   frag[j] = W_side[k][d = s*32 + (lane>>4)*8 + j][e = (h*4+et')*16 + (lane&15)]
// wsV: unit cs*64+lane: frag[j] = V[lane&15][c = cs*32 + (lane>>4)*8 + j]
__global__ void ntn_prep(const float* __restrict__ W1, const float* __restrict__ W2,
                         const float* __restrict__ V,
                         unsigned short* __restrict__ wsW, unsigned short* __restrict__ wsV) {
  int t = blockIdx.x * 256 + threadIdx.x;
  if (t < 65536) {
    int u = t & 2047;
    int lane = u & 63, s = (u >> 6) & 3, et2 = (u >> 8) & 3, side = (u >> 10) & 1;
    int cc = t >> 11, h = cc & 1, k = cc >> 1;
    int q = lane >> 4, l15 = lane & 15;
    int et = h * 4 + et2;
    const float* W = side ? W2 : W1;
    const float* src = W + k * 16384 + (s * 32 + q * 8) * 128 + (et * 16 + l15);
    us8 r;
#pragma unroll
    for (int j = 0; j < 8; ++j) r[j] = f2bf(src[j * 128]);
    *(us8*)(wsW + (size_t)t * 8) = r;
  } else if (t < 66048) {
    int u = t - 65536;
    int lane = u & 63, cs = u >> 6;
    int q = lane >> 4, l15 = lane & 15;
    const float* src = V + l15 * 256 + cs * 32 + q * 8;
    us8 r;
#pragma unroll
    for (int j = 0; j < 8; ++j) r[j] = f2bf(src[j]);
    *(us8*)(wsV + (size_t)u * 8) = r;
  }
}

// ---------------- main ----------------
__global__ __launch_bounds__(512, 2) void ntn_main(
    const float* __restrict__ x1, const float* __restrict__ x2,
    const float* __restrict__ b,
    const unsigned short* __restrict__ wsW, const unsigned short* __restrict__ wsV,
    float* __restrict__ out) {
  __shared__ uint4 ldsW[2][2048];   // two 32KB chunk slots = 64KB

  const int tid = threadIdx.x;
  const int lane = tid & 63, wave = tid >> 6;   // wave 0..7
  const int q = lane >> 4, l15 = lane & 15;

  // XCD-major block mapping: blocks dispatch round-robin across 8 XCDs, so
  // bi&7 is the XCD. Give each XCD a contiguous 16-rb slab; within it the
  // 4 kq-blocks of one rb are adjacent (same XCD -> out-line quarters merge).
  const int bi = blockIdx.x;
  const int xcd = bi & 7, jj = bi >> 3;
  const int rb = xcd * 16 + (jj >> 2);    // 0..127: 256-row group
  const int kq = jj & 3;                  // k range [kq*4, kq*4+4)
  const int rowbase = rb * 256 + wave * 32;

  const f32x4 zero4 = {0.f, 0.f, 0.f, 0.f};

  // async stage of one 32KB chunk into an LDS slot (4 glds x 64 lanes x 16B / wave)
  auto stage = [&](int cc, int slot) {
    const unsigned short* src = wsW + (size_t)cc * 16384 + (size_t)(wave * 256 + lane) * 8;
    uint4* dst = &ldsW[slot][wave * 256];
#pragma unroll
    for (int i = 0; i < 4; ++i)
      __builtin_amdgcn_global_load_lds(
          (__attribute__((address_space(1))) void*)(void*)(src + i * 512),
          (__attribute__((address_space(3))) void*)(dst + i * 64), 16, 0, 0);
  };

  stage(kq * 8, 0);   // first chunk of our k range

  // ---- X fragments (B-operand), bf16, k-invariant, in registers ----
  // frag[j] = X[row = rowbase + nt*16 + (lane&15)][d = s*32 + (lane>>4)*8 + j]
  bf16x8 xb[2][2][4];
#pragma unroll
  for (int side = 0; side < 2; ++side) {
    const float* xp0 = side ? x2 : x1;
#pragma unroll
    for (int nt = 0; nt < 2; ++nt) {
#pragma unroll
      for (int s = 0; s < 4; ++s) {
        const float* p = xp0 + (size_t)(rowbase + nt * 16 + l15) * 128 + s * 32 + q * 8;
        float4 v0 = *(const float4*)p;
        float4 v1 = *(const float4*)(p + 4);
        us8 uu;
        uu[0] = f2bf(v0.x); uu[1] = f2bf(v0.y); uu[2] = f2bf(v0.z); uu[3] = f2bf(v0.w);
        uu[4] = f2bf(v1.x); uu[5] = f2bf(v1.y); uu[6] = f2bf(v1.z); uu[7] = f2bf(v1.w);
        xb[side][nt][s] = as_bf(uu);
      }
    }
  }

  // ---- part2 + b via MFMA (A = V frags: M=k; B = X frags), kept in registers ----
  f32x4 accP[2];
  {
    bf16x8 vf[8];
#pragma unroll
    for (int cs = 0; cs < 8; ++cs)
      vf[cs] = as_bf(*(const us8*)(wsV + (size_t)(cs * 64 + lane) * 8));
    float4 bv = *(const float4*)(b + q * 4);
#pragma unroll
    for (int nt = 0; nt < 2; ++nt) {
      f32x4 a = zero4;
#pragma unroll
      for (int cs = 0; cs < 8; ++cs)
        a = __builtin_amdgcn_mfma_f32_16x16x32_bf16(vf[cs], xb[cs >> 2][nt][cs & 3], a, 0, 0, 0);
      a.x += bv.x; a.y += bv.y; a.z += bv.z; a.w += bv.w;
      accP[nt] = a;   // lane quad q holds part2+b for k = q*4 + reg
    }
  }

  float nm[2] = {0.f, 0.f}, q1[2] = {0.f, 0.f}, q2[2] = {0.f, 0.f};

  // compute one e-half (4 e-tiles, both sides) from an LDS slot, fold reductions
  auto compute = [&](int slot) {
#pragma unroll
    for (int et = 0; et < 4; ++et) {
      bf16x8 wa[4], wb[4];
#pragma unroll
      for (int s = 0; s < 4; ++s) {
        wa[s] = as_bf(*(const us8*)&ldsW[slot][et * 256 + s * 64 + lane]);
        wb[s] = as_bf(*(const us8*)&ldsW[slot][1024 + et * 256 + s * 64 + lane]);
      }
#pragma unroll
      for (int nt = 0; nt < 2; ++nt) {
        f32x4 a1 = zero4, a2 = zero4;
#pragma unroll
        for (int s = 0; s < 4; ++s)
          a1 = __builtin_amdgcn_mfma_f32_16x16x32_bf16(wa[s], xb[0][nt][s], a1, 0, 0, 0);
#pragma unroll
        for (int s = 0; s < 4; ++s)
          a2 = __builtin_amdgcn_mfma_f32_16x16x32_bf16(wb[s], xb[1][nt][s], a2, 0, 0, 0);
        nm[nt] += a1.x * a2.x + a1.y * a2.y + a1.z * a2.z + a1.w * a2.w;
        q1[nt] += a1.x * a1.x + a1.y * a1.y + a1.z * a1.z + a1.w * a1.w;
        q2[nt] += a2.x * a2.x + a2.y * a2.y + a2.z * a2.z + a2.w * a2.w;
      }
    }
  };

#pragma unroll 1
  for (int kk = 0; kk < 4; ++kk) {
    const int cbase = kq * 8 + 2 * kk;
    __syncthreads();                       // chunk (kk, h=0) in slot0; slot1 free
    stage(cbase + 1, 1);
    compute(0);
    __syncthreads();                       // chunk (kk, h=1) in slot1; slot0 free
    if (kk < 3) stage(cbase + 2, 0);
    compute(1);

    const int k = kq * 4 + kk;
    const int qo = k >> 2;                 // owning lane quad (== kq)
    const int r  = k & 3;
#pragma unroll
    for (int nt = 0; nt < 2; ++nt) {
      float n = nm[nt], s1 = q1[nt], s2 = q2[nt];
      n  += __shfl_xor(n, 16);  n  += __shfl_xor(n, 32);
      s1 += __shfl_xor(s1, 16); s1 += __shfl_xor(s1, 32);
      s2 += __shfl_xor(s2, 16); s2 += __shfl_xor(s2, 32);
      float d1 = fmaxf(sqrtf(s1), 1e-8f);
      float d2 = fmaxf(sqrtf(s2), 1e-8f);
      float p1 = n / (d1 * d2);
      float pc = (r == 0) ? accP[nt].x : (r == 1) ? accP[nt].y
               : (r == 2) ? accP[nt].z : accP[nt].w;
      if (q == qo)
        out[(size_t)(rowbase + nt * 16 + l15) * 16 + k] = fmaxf(p1 + pc, 0.f);
      nm[nt] = 0.f; q1[nt] = 0.f; q2[nt] = 0.f;
    }
  }
}

extern "C" void kernel_launch(void* const* d_in, const int* in_sizes, int n_in,
                              void* d_out, int out_size, void* d_ws, size_t ws_size,
                              hipStream_t stream) {
  const float* x1 = (const float*)d_in[0];
  const float* x2 = (const float*)d_in[1];
  const float* W1 = (const float*)d_in[2];
  const float* W2 = (const float*)d_in[3];
  const float* V  = (const float*)d_in[4];
  const float* b  = (const float*)d_in[5];
  float* out = (float*)d_out;
  unsigned short* wsW = (unsigned short*)d_ws;
  unsigned short* wsV = wsW + (size_t)65536 * 8;   // 1MB offset

  ntn_prep<<<258, 256, 0, stream>>>(W1, W2, V, wsW, wsV);
  ntn_main<<<512, 512, 0, stream>>>(x1, x2, b, wsW, wsV, out);
}

// Round 4
// 119.914 us; speedup vs baseline: 2.0129x; 1.0373x over previous
//
#include <hip/hip_runtime.h>

// NTN: out[n,k] = relu( cos(x1 @ W1[k], x2 @ W2[k]) + [x1,x2]·V[k] + b[k] )
// N=32768, D=128, K=16.
// R7 = R3 (49us champion: 256thr/4 waves, 512 blocks, 2 blk/CU) with the
// barrier-drain removed via counted-vmcnt half-pipelining (guide T3+T4).
// R3..R6 evidence: occupancy-raising restructures (R4/R6) did NOT help; R3 is
// schedule-stalled: 16x per block __syncthreads drains vmcnt(0), serializing
// all waves. Fix = stage 16KB side-halves into a ring of 4 LDS slots; before
// each compute: s_waitcnt vmcnt(4 or 6) (never 0 mid-loop) + raw s_barrier,
// so prefetched global_load_lds stay in flight ACROSS barriers.
//  - half h (0..31): chunk cc = kh*16 + (h>>1), side = h&1, slot = h&3.
//    Identity LDS layout within the half (no permutation — R5's failure was in
//    a permuted-quarter variant; avoided).
//  - computeA (side0) accumulates a1[4][2] (32 VGPR, static idx);
//    computeB (side1) computes a2 and folds nm/q1/q2.  Same MFMA count/math.
//  - vmcnt immediates from FIFO accounting incl. 2 epilogue stores per k:
//    k0=[4,4,4,4], k1..6=[6,6,4,4], k7=[6,6,4,0(final drain)].
//  - T5 setprio(1) around MFMA clusters.

typedef __attribute__((ext_vector_type(8))) __bf16 bf16x8;
typedef __attribute__((ext_vector_type(8))) unsigned short us8;
typedef __attribute__((ext_vector_type(4))) float f32x4;

static __device__ __forceinline__ unsigned short f2bf(float f) {
  unsigned u = __float_as_uint(f);
  u += 0x7FFFu + ((u >> 16) & 1u);   // round-to-nearest-even
  return (unsigned short)(u >> 16);
}

static __device__ __forceinline__ bf16x8 as_bf(us8 u) {
  bf16x8 r;
  __builtin_memcpy(&r, &u, sizeof(r));
  return r;
}

template <int VM>
static __device__ __forceinline__ void waitbar() {
  asm volatile("s_waitcnt vmcnt(%0)" :: "i"(VM) : "memory");
  __builtin_amdgcn_s_barrier();
  __builtin_amdgcn_sched_barrier(0);
}

// ---------------- prep (UNCHANGED) ----------------
// wsW: 32 chunks (cc = k*2 + h) of 2048 16B-units.
//   unit u: side=(u>>10)&1, et'=(u>>8)&3, s=(u>>6)&3, lane=u&63.
//   frag[j] = W_side[k][d = s*32 + (lane>>4)*8 + j][e = (h*4+et')*16 + (lane&15)]
// wsV: unit cs*64+lane: frag[j] = V[lane&15][c = cs*32 + (lane>>4)*8 + j]
__global__ void ntn_prep(const float* __restrict__ W1, const float* __restrict__ W2,
                         const float* __restrict__ V,
                         unsigned short* __restrict__ wsW, unsigned short* __restrict__ wsV) {
  int t = blockIdx.x * 256 + threadIdx.x;
  if (t < 65536) {
    int u = t & 2047;
    int lane = u & 63, s = (u >> 6) & 3, et2 = (u >> 8) & 3, side = (u >> 10) & 1;
    int cc = t >> 11, h = cc & 1, k = cc >> 1;
    int q = lane >> 4, l15 = lane & 15;
    int et = h * 4 + et2;
    const float* W = side ? W2 : W1;
    const float* src = W + k * 16384 + (s * 32 + q * 8) * 128 + (et * 16 + l15);
    us8 r;
#pragma unroll
    for (int j = 0; j < 8; ++j) r[j] = f2bf(src[j * 128]);
    *(us8*)(wsW + (size_t)t * 8) = r;
  } else if (t < 66048) {
    int u = t - 65536;
    int lane = u & 63, cs = u >> 6;
    int q = lane >> 4, l15 = lane & 15;
    const float* src = V + l15 * 256 + cs * 32 + q * 8;
    us8 r;
#pragma unroll
    for (int j = 0; j < 8; ++j) r[j] = f2bf(src[j]);
    *(us8*)(wsV + (size_t)u * 8) = r;
  }
}

// ---------------- main ----------------
__global__ __launch_bounds__(256, 2) void ntn_main(
    const float* __restrict__ x1, const float* __restrict__ x2,
    const float* __restrict__ b,
    const unsigned short* __restrict__ wsW, const unsigned short* __restrict__ wsV,
    float* __restrict__ out) {
  __shared__ uint4 ldsH[4][1024];   // ring of four 16KB half-slots = 64KB

  const int tid = threadIdx.x;
  const int lane = tid & 63, wave = tid >> 6;
  const int q = lane >> 4, l15 = lane & 15;
  const int kh = blockIdx.x & 1;          // k range [8kh, 8kh+8)
  const int rb = blockIdx.x >> 1;         // 128-row group
  const int rowbase = rb * 128 + wave * 32;

  const f32x4 zero4 = {0.f, 0.f, 0.f, 0.f};

  // async stage of one 16KB side-half into a ring slot
  // (4 glds x 64 lanes x 16B per wave; 4 waves cover the 16KB)
  auto stage = [&](int cc, int side, int slot) {
    const unsigned short* src =
        wsW + ((size_t)cc * 2048 + side * 1024 + wave * 256 + lane) * 8;
    uint4* dst = &ldsH[slot][wave * 256];
#pragma unroll
    for (int i = 0; i < 4; ++i)
      __builtin_amdgcn_global_load_lds(
          (__attribute__((address_space(1))) void*)(void*)(src + i * 512),
          (__attribute__((address_space(3))) void*)(dst + i * 64), 16, 0, 0);
  };

  // ---- X fragments (B-operand), bf16, k-invariant, in registers ----
  // frag[j] = X[row = rowbase + nt*16 + (lane&15)][d = s*32 + (lane>>4)*8 + j]
  bf16x8 xb[2][2][4];
#pragma unroll
  for (int side = 0; side < 2; ++side) {
    const float* xp0 = side ? x2 : x1;
#pragma unroll
    for (int nt = 0; nt < 2; ++nt) {
#pragma unroll
      for (int s = 0; s < 4; ++s) {
        const float* p = xp0 + (size_t)(rowbase + nt * 16 + l15) * 128 + s * 32 + q * 8;
        float4 v0 = *(const float4*)p;
        float4 v1 = *(const float4*)(p + 4);
        us8 uu;
        uu[0] = f2bf(v0.x); uu[1] = f2bf(v0.y); uu[2] = f2bf(v0.z); uu[3] = f2bf(v0.w);
        uu[4] = f2bf(v1.x); uu[5] = f2bf(v1.y); uu[6] = f2bf(v1.z); uu[7] = f2bf(v1.w);
        xb[side][nt][s] = as_bf(uu);
      }
    }
  }

  // ---- part2 + b via MFMA (A = V frags: M=k; B = X frags), kept in registers ----
  f32x4 accP[2];
  {
    bf16x8 vf[8];
#pragma unroll
    for (int cs = 0; cs < 8; ++cs)
      vf[cs] = as_bf(*(const us8*)(wsV + (size_t)(cs * 64 + lane) * 8));
    float4 bv = *(const float4*)(b + q * 4);
#pragma unroll
    for (int nt = 0; nt < 2; ++nt) {
      f32x4 a = zero4;
#pragma unroll
      for (int cs = 0; cs < 8; ++cs)
        a = __builtin_amdgcn_mfma_f32_16x16x32_bf16(vf[cs], xb[cs >> 2][nt][cs & 3], a, 0, 0, 0);
      a.x += bv.x; a.y += bv.y; a.z += bv.z; a.w += bv.w;
      accP[nt] = a;   // lane quad q holds part2+b for k = q*4 + reg
    }
  }

  float nm[2] = {0.f, 0.f}, q1[2] = {0.f, 0.f}, q2[2] = {0.f, 0.f};
  f32x4 a1[4][2];   // side0 accumulators, live from computeA to computeB

  // side0 half: accumulate a1[et][nt]
  auto computeA = [&](int slot) {
#pragma unroll
    for (int et = 0; et < 4; ++et) {
      bf16x8 wa[4];
#pragma unroll
      for (int s = 0; s < 4; ++s)
        wa[s] = as_bf(*(const us8*)&ldsH[slot][et * 256 + s * 64 + lane]);
      __builtin_amdgcn_s_setprio(1);
#pragma unroll
      for (int nt = 0; nt < 2; ++nt) {
        f32x4 a = zero4;
#pragma unroll
        for (int s = 0; s < 4; ++s)
          a = __builtin_amdgcn_mfma_f32_16x16x32_bf16(wa[s], xb[0][nt][s], a, 0, 0, 0);
        a1[et][nt] = a;
      }
      __builtin_amdgcn_s_setprio(0);
    }
  };

  // side1 half: compute a2 and fold nm/q1/q2 against stored a1
  auto computeB = [&](int slot) {
#pragma unroll
    for (int et = 0; et < 4; ++et) {
      bf16x8 wb[4];
#pragma unroll
      for (int s = 0; s < 4; ++s)
        wb[s] = as_bf(*(const us8*)&ldsH[slot][et * 256 + s * 64 + lane]);
      __builtin_amdgcn_s_setprio(1);
#pragma unroll
      for (int nt = 0; nt < 2; ++nt) {
        f32x4 a2 = zero4;
#pragma unroll
        for (int s = 0; s < 4; ++s)
          a2 = __builtin_amdgcn_mfma_f32_16x16x32_bf16(wb[s], xb[1][nt][s], a2, 0, 0, 0);
        f32x4 v1 = a1[et][nt];
        nm[nt] += v1.x * a2.x + v1.y * a2.y + v1.z * a2.z + v1.w * a2.w;
        q1[nt] += v1.x * v1.x + v1.y * v1.y + v1.z * v1.z + v1.w * v1.w;
        q2[nt] += a2.x * a2.x + a2.y * a2.y + a2.z * a2.z + a2.w * a2.w;
      }
      __builtin_amdgcn_s_setprio(0);
    }
  };

  auto epilogue = [&](int k) {
    const int qo = k >> 2;
    const int r  = k & 3;
#pragma unroll
    for (int nt = 0; nt < 2; ++nt) {
      float n = nm[nt], s1 = q1[nt], s2 = q2[nt];
      n  += __shfl_xor(n, 16);  n  += __shfl_xor(n, 32);
      s1 += __shfl_xor(s1, 16); s1 += __shfl_xor(s1, 32);
      s2 += __shfl_xor(s2, 16); s2 += __shfl_xor(s2, 32);
      float d1 = fmaxf(sqrtf(s1), 1e-8f);
      float d2 = fmaxf(sqrtf(s2), 1e-8f);
      float p1 = n / (d1 * d2);
      float pc = (r == 0) ? accP[nt].x : (r == 1) ? accP[nt].y
               : (r == 2) ? accP[nt].z : accP[nt].w;
      if (q == qo)
        out[(size_t)(rowbase + nt * 16 + l15) * 16 + k] = fmaxf(p1 + pc, 0.f);
      nm[nt] = 0.f; q1[nt] = 0.f; q2[nt] = 0.f;
    }
  };

  // Prologue: first chunk's two side-halves into slots 0,1 (8 loads in flight).
  {
    const int c0 = kh * 16;
    stage(c0, 0, 0);
    stage(c0, 1, 1);
  }

  // One k-step = 4 half-intervals. Stages keep 2 halves (8 loads) in flight;
  // vmcnt(N) waits only for the half about to be read (FIFO-exact, see header).
#define KSTEP(V0, V1, V2, V3, DO23, C0, KIDX)                \
  do {                                                       \
    waitbar<V0>(); stage((C0) + 1, 0, 2); computeA(0);       \
    waitbar<V1>(); stage((C0) + 1, 1, 3); computeB(1);       \
    waitbar<V2>(); if (DO23) stage((C0) + 2, 0, 0); computeA(2); \
    waitbar<V3>(); if (DO23) stage((C0) + 2, 1, 1); computeB(3); \
    epilogue(KIDX);                                          \
  } while (0)

  { KSTEP(4, 4, 4, 4, true, kh * 16, kh * 8); }
#pragma unroll 1
  for (int kk = 1; kk < 7; ++kk) {
    KSTEP(6, 6, 4, 4, true, kh * 16 + 2 * kk, kh * 8 + kk);
  }
  { KSTEP(6, 6, 4, 0, false, kh * 16 + 14, kh * 8 + 7); }
#undef KSTEP
}

extern "C" void kernel_launch(void* const* d_in, const int* in_sizes, int n_in,
                              void* d_out, int out_size, void* d_ws, size_t ws_size,
                              hipStream_t stream) {
  const float* x1 = (const float*)d_in[0];
  const float* x2 = (const float*)d_in[1];
  const float* W1 = (const float*)d_in[2];
  const float* W2 = (const float*)d_in[3];
  const float* V  = (const float*)d_in[4];
  const float* b  = (const float*)d_in[5];
  float* out = (float*)d_out;
  unsigned short* wsW = (unsigned short*)d_ws;
  unsigned short* wsV = wsW + (size_t)65536 * 8;   // 1MB offset

  ntn_prep<<<258, 256, 0, stream>>>(W1, W2, V, wsW, wsV);
  ntn_main<<<512, 256, 0, stream>>>(x1, x2, b, wsW, wsV, out);
}